// Round 1
// baseline (335.985 us; speedup 1.0000x reference)
//
#include <hip/hip_runtime.h>
#include <hip/hip_bf16.h>
#include <stdint.h>

// Problem dims (fixed by reference)
#define BB 8
#define NN 8192
#define DD 512
#define HH 8
#define DHD 64
#define NCH 32   // kv partial chunks (each = 256 rows = 4 tiles of 64)

typedef __attribute__((ext_vector_type(8))) short bf16x8;
typedef __attribute__((ext_vector_type(4))) float f32x4;
typedef __attribute__((ext_vector_type(4))) float f4v;

__device__ __forceinline__ unsigned short f2bf(float f) {
  union { float f; unsigned int u; } v; v.f = f;
  return (unsigned short)((v.u + 0x7FFFu + ((v.u >> 16) & 1u)) >> 16);
}

__device__ __forceinline__ void async16(const void* g, void* l) {
  __builtin_amdgcn_global_load_lds(
      (const __attribute__((address_space(1))) void*)g,
      (__attribute__((address_space(3))) void*)l, 16, 0, 0);
}

// ---------------- Kernel 1: fused RoPE + cast + per-head X_h^T X_h partials ----
// grid (nb*32) blocks of 512 thr (8 waves). Block = 256 rows (4 tiles of 64).
// Wave w owns head w: full 64x64 accumulator (16 MFMAs/ks, B-frag == A-frag since
// kv is symmetric and both operands want [d][n] layout).
// Table trick: cos[n][d+256] == cos[n][d] (reference concatenates ang with itself),
// so only the lo-half tables are read.
__global__ __launch_bounds__(512, 2) void ropekv_kernel(
    const float* __restrict__ h, const float* __restrict__ cs,
    const float* __restrict__ sn, unsigned short* __restrict__ x,
    float* __restrict__ kvp, int nbh) {
  // [d=512][np=32] packed bf16 row-pairs; pitch 34 u32 = 68 shorts (2-way-free reads,
  // same read idiom as the previously verified kv kernel).
  __shared__ __align__(16) unsigned int xt32[512 * 34];  // 69.6 KB
  int blk = blockIdx.x;
  int chunk = blk & 31, b = blk >> 5;
  int tid = threadIdx.x;
  int wave = tid >> 6, lane = tid & 63;
  int rpar = lane & 1;          // row parity within pair
  int g = lane >> 1;            // col-group [0,32): 8 fp32 cols each
  int cf = g * 8;               // fp32 col base in lo half [0,256)
  int l15 = lane & 15, q = lane >> 4;
  int hd = wave * 64;           // head d-base for MFMA phase
  size_t row0 = (size_t)b * NN + (size_t)chunk * 256;
  int n0 = chunk * 256;

  f32x4 acc[4][4];
#pragma unroll
  for (int i = 0; i < 4; ++i)
#pragma unroll
    for (int j = 0; j < 4; ++j) acc[i][j] = (f32x4){0.f, 0.f, 0.f, 0.f};

  f4v ha[4][2], hbv[4][2];  // tile-t h values: [pass][lo/hi-halves as 2 f4v each]

  auto loadt = [&](int t) {
#pragma unroll
    for (int p = 0; p < 4; ++p) {
      int r = p * 16 + wave * 2 + rpar;
      const float* hp = h + (row0 + t * 64 + r) * DD + cf;
      ha[p][0]  = __builtin_nontemporal_load((const f4v*)hp);
      ha[p][1]  = __builtin_nontemporal_load((const f4v*)(hp + 4));
      hbv[p][0] = __builtin_nontemporal_load((const f4v*)(hp + 256));
      hbv[p][1] = __builtin_nontemporal_load((const f4v*)(hp + 260));
    }
  };

  auto ropet = [&](int t) {
#pragma unroll
    for (int p = 0; p < 4; ++p) {
      int r = p * 16 + wave * 2 + rpar;
      int nr = n0 + t * 64 + r;
      const float* cp = cs + (size_t)nr * DD + cf;
      const float* sp = sn + (size_t)nr * DD + cf;
      f4v c0 = *(const f4v*)cp, c1 = *(const f4v*)(cp + 4);
      f4v s0 = *(const f4v*)sp, s1 = *(const f4v*)(sp + 4);
      f4v xl0 = ha[p][0] * c0 - hbv[p][0] * s0;   // cols cf..cf+8
      f4v xl1 = ha[p][1] * c1 - hbv[p][1] * s1;
      f4v xh0 = hbv[p][0] * c0 + ha[p][0] * s0;   // cols cf+256..
      f4v xh1 = hbv[p][1] * c1 + ha[p][1] * s1;
      unsigned ml[4], mh[4];
      ml[0] = (unsigned)f2bf(xl0.x) | ((unsigned)f2bf(xl0.y) << 16);
      ml[1] = (unsigned)f2bf(xl0.z) | ((unsigned)f2bf(xl0.w) << 16);
      ml[2] = (unsigned)f2bf(xl1.x) | ((unsigned)f2bf(xl1.y) << 16);
      ml[3] = (unsigned)f2bf(xl1.z) | ((unsigned)f2bf(xl1.w) << 16);
      mh[0] = (unsigned)f2bf(xh0.x) | ((unsigned)f2bf(xh0.y) << 16);
      mh[1] = (unsigned)f2bf(xh0.z) | ((unsigned)f2bf(xh0.w) << 16);
      mh[2] = (unsigned)f2bf(xh1.x) | ((unsigned)f2bf(xh1.y) << 16);
      mh[3] = (unsigned)f2bf(xh1.z) | ((unsigned)f2bf(xh1.w) << 16);
      // global x store (coalesced: lane-pairs interleave two rows, union contiguous)
      unsigned short* xp = x + (row0 + t * 64 + r) * DD + cf;
      uint4 st0; st0.x = ml[0]; st0.y = ml[1]; st0.z = ml[2]; st0.w = ml[3];
      uint4 st1; st1.x = mh[0]; st1.y = mh[1]; st1.z = mh[2]; st1.w = mh[3];
      *(uint4*)xp         = st0;
      *(uint4*)(xp + 256) = st1;
      // row-pair pack via partner exchange: even lane writes its 8 lo-d packs,
      // odd lane the 8 hi-d packs (d+256).
      unsigned pk[8];
#pragma unroll
      for (int k = 0; k < 4; ++k) {
        unsigned mine = rpar ? mh[k] : ml[k];
        unsigned send = rpar ? ml[k] : mh[k];
        unsigned recv = (unsigned)__shfl_xor((int)send, 1, 64);
        if (!rpar) {
          pk[2 * k]     = (mine & 0xffffu) | (recv << 16);
          pk[2 * k + 1] = (mine >> 16) | (recv & 0xffff0000u);
        } else {
          pk[2 * k]     = (recv & 0xffffu) | (mine << 16);
          pk[2 * k + 1] = (recv >> 16) | (mine & 0xffff0000u);
        }
      }
      int np = p * 8 + wave;                  // row-pair index within tile [0,32)
      int dbase = cf + (rpar ? 256 : 0);
      int rot = (g >> 1) & 7;                 // lane-rotated write order: 16-bank spread, <=4-way
#pragma unroll
      for (int w = 0; w < 8; ++w) {
        int jj = (w + rot) & 7;
        xt32[(dbase + jj) * 34 + np] = pk[jj];
      }
    }
  };

  loadt(0);
  for (int t = 0; t < 4; ++t) {
    ropet(t);            // consumes tile-t loads, writes x + transposed LDS
    __syncthreads();     // xt ready
    if (t < 3) loadt(t + 1);   // issue next tile's global loads before MFMA (hide latency)
    const unsigned short* xt16 = (const unsigned short*)xt32;
#pragma unroll
    for (int ks = 0; ks < 64; ks += 32) {
      bf16x8 af[4];
#pragma unroll
      for (int i = 0; i < 4; ++i)
        af[i] = *(const bf16x8*)&xt16[(hd + i * 16 + l15) * 68 + ks + q * 8];
#pragma unroll
      for (int i = 0; i < 4; ++i)
#pragma unroll
        for (int j = 0; j < 4; ++j)
          acc[i][j] = __builtin_amdgcn_mfma_f32_16x16x32_bf16(af[i], af[j], acc[i][j], 0, 0, 0);
    }
    __syncthreads();     // xt consumable by next tile's writes
  }

  int bh = b * 8 + wave;
  float* dst = kvp + ((size_t)chunk * nbh + bh) * 4096;
#pragma unroll
  for (int i = 0; i < 4; ++i)
#pragma unroll
    for (int j = 0; j < 4; ++j)
#pragma unroll
      for (int reg = 0; reg < 4; ++reg)
        dst[(i * 16 + q * 4 + reg) * 64 + j * 16 + l15] = acc[i][j][reg];
}

// ---------------- Kernel 2: sum kv partials once, WkvT[bh][e][f] = sum_d W[h*64+d][f]*kv[d][e]
// grid (nbh*4): bh x e-quarter. Each block reads its kvp slice exactly once.
__global__ __launch_bounds__(512, 2) void wkvt_kernel(
    const float* __restrict__ W, const float* __restrict__ kvp,
    unsigned short* __restrict__ wkvt, int nbh) {
  __shared__ float kvs[64 * 16];                    // [d][16 e]  4 KB
  __shared__ __align__(16) float ws[64 * 512];      // [d][f] 128 KB
  int blk = blockIdx.x;
  int bh = blk >> 2, eq = blk & 3;
  int b = bh >> 3, hh = bh & 7;
  int tid = threadIdx.x;
  if (tid < 256) {
    int idx = tid * 4;
    int d = idx >> 4, ec = idx & 15;
    f4v s = (f4v){0.f, 0.f, 0.f, 0.f};
    for (int c = 0; c < NCH; ++c)
      s += *(const f4v*)&kvp[((size_t)c * nbh + bh) * 4096 + d * 64 + eq * 16 + ec];
    *(f4v*)&kvs[idx] = s;
  }
#pragma unroll
  for (int i = 0; i < 16; ++i) {
    int idx = i * 2048 + tid * 4;
    *(f4v*)&ws[idx] = *(const f4v*)&W[(size_t)(hh * DHD + (idx >> 9)) * DD + (idx & 511)];
  }
  __syncthreads();
  int el = tid & 15, fg = tid >> 4;   // e-local [0,16), f-group of 16 [0,32)
  f4v av[4];
#pragma unroll
  for (int k = 0; k < 4; ++k) av[k] = (f4v){0.f, 0.f, 0.f, 0.f};
#pragma unroll 8
  for (int d = 0; d < 64; ++d) {
    float kvv = kvs[d * 16 + el];                     // broadcast within 16-lane groups
    const f4v* wr = (const f4v*)&ws[d * DD + fg * 16];  // wave-half-uniform broadcast
#pragma unroll
    for (int k = 0; k < 4; ++k) av[k] += wr[k] * kvv;
  }
  unsigned short tb[16];
#pragma unroll
  for (int k = 0; k < 4; ++k) {
    tb[k * 4 + 0] = f2bf(av[k].x); tb[k * 4 + 1] = f2bf(av[k].y);
    tb[k * 4 + 2] = f2bf(av[k].z); tb[k * 4 + 3] = f2bf(av[k].w);
  }
  size_t ob = ((size_t)b * DD + hh * DHD + eq * 16 + el) * DD + fg * 16;
  *(uint4*)&wkvt[ob]     = *(uint4*)&tb[0];
  *(uint4*)&wkvt[ob + 8] = *(uint4*)&tb[8];
}

// ---------------- Kernel 3: out[b] = x_b [8192x512] @ WkvT_b^T  (bf16 MFMA, fp32 out) ----
// 128x256 block tile, 4 waves each 64x128 (4x8 of 16x16). grid (64, 2, nb).
__global__ __launch_bounds__(256, 2) void gemm_kernel(const unsigned short* __restrict__ x,
                                                      const unsigned short* __restrict__ wkvt,
                                                      float* __restrict__ out) {
  __shared__ __align__(16) unsigned short As[128 * 64];  // [m][k] 16 KB
  __shared__ __align__(16) unsigned short Bs[256 * 64];  // [c][k] 32 KB
  int mt = blockIdx.x, ct = blockIdx.y, bz = blockIdx.z;
  int tid = threadIdx.x, wave = tid >> 6, lane = tid & 63;
  int m_off = (wave & 1) * 64, c_off = (wave >> 1) * 128;
  int l15 = lane & 15, q = lane >> 4;
  int lrow = lane >> 3, lcol = (lane & 7) * 8;
  const unsigned short* Ag = x    + ((size_t)bz * NN + mt * 128) * DD;
  const unsigned short* Bg = wkvt + ((size_t)bz * DD + ct * 256) * DD;
  f32x4 acc[4][8];
#pragma unroll
  for (int i = 0; i < 4; ++i)
#pragma unroll
    for (int j = 0; j < 8; ++j) acc[i][j] = (f32x4){0.f, 0.f, 0.f, 0.f};

  for (int kk = 0; kk < 512; kk += 64) {
#pragma unroll
    for (int i = 0; i < 4; ++i)
      async16(Ag + (size_t)(wave * 32 + i * 8 + lrow) * DD + kk + lcol,
              &As[(wave * 32 + i * 8) * 64]);
#pragma unroll
    for (int i = 0; i < 8; ++i)
      async16(Bg + (size_t)(wave * 64 + i * 8 + lrow) * DD + kk + lcol,
              &Bs[(wave * 64 + i * 8) * 64]);
    __syncthreads();
#pragma unroll
    for (int ks = 0; ks < 64; ks += 32) {
      bf16x8 a[4], bb[8];
#pragma unroll
      for (int i = 0; i < 4; ++i)
        a[i] = *(const bf16x8*)&As[(m_off + i * 16 + l15) * 64 + ks + q * 8];
#pragma unroll
      for (int j = 0; j < 8; ++j)
        bb[j] = *(const bf16x8*)&Bs[(c_off + j * 16 + l15) * 64 + ks + q * 8];
#pragma unroll
      for (int i = 0; i < 4; ++i)
#pragma unroll
        for (int j = 0; j < 8; ++j)
          acc[i][j] = __builtin_amdgcn_mfma_f32_16x16x32_bf16(a[i], bb[j], acc[i][j], 0, 0, 0);
    }
    __syncthreads();
  }
  float* ob = out + ((size_t)bz * NN + mt * 128) * DD + ct * 256;
#pragma unroll
  for (int i = 0; i < 4; ++i)
#pragma unroll
    for (int j = 0; j < 8; ++j) {
      int row = m_off + i * 16 + q * 4;
      int col = c_off + j * 16 + l15;
#pragma unroll
      for (int reg = 0; reg < 4; ++reg)
        __builtin_nontemporal_store(acc[i][j][reg], &ob[(size_t)(row + reg) * DD + col]);
    }
}

extern "C" void kernel_launch(void* const* d_in, const int* in_sizes, int n_in,
                              void* d_out, int out_size, void* d_ws, size_t ws_size,
                              hipStream_t stream) {
  (void)in_sizes; (void)n_in; (void)out_size;
  const float* h  = (const float*)d_in[0];
  const float* W  = (const float*)d_in[1];
  const float* cs = (const float*)d_in[2];
  const float* sn = (const float*)d_in[3];
  float* out = (float*)d_out;

  const size_t x_full     = (size_t)BB * NN * DD * 2;               // 67.1 MB
  const size_t kvp_full   = (size_t)NCH * BB * HH * DHD * DHD * 4;  // 33.6 MB
  const size_t wkvt_full  = (size_t)BB * DD * DD * 2;               // 4.2 MB
  const size_t x_batch    = (size_t)NN * DD * 2;                    // 8.4 MB
  const size_t kvp_batch  = (size_t)NCH * HH * DHD * DHD * 4;       // 4.2 MB
  const size_t wkvt_batch = (size_t)DD * DD * 2;                    // 524 KB

  if (ws_size >= x_full + kvp_full + wkvt_full) {
    // -------- full path: 3 launches --------
    unsigned short* xw   = (unsigned short*)d_ws;
    float*          kvp  = (float*)((char*)d_ws + x_full);
    unsigned short* wkvt = (unsigned short*)((char*)d_ws + x_full + kvp_full);
    ropekv_kernel<<<dim3(BB * 32), dim3(512), 0, stream>>>(h, cs, sn, xw, kvp, BB * HH);
    wkvt_kernel<<<dim3(BB * HH * 4), dim3(512), 0, stream>>>(W, kvp, wkvt, BB * HH);
    gemm_kernel<<<dim3(NN / 128, DD / 256, BB), dim3(256), 0, stream>>>(xw, wkvt, out);
  } else {
    // -------- per-batch fallback (~13 MB workspace) --------
    unsigned short* xw   = (unsigned short*)d_ws;
    float*          kvp  = (float*)((char*)d_ws + x_batch);
    unsigned short* wkvt = (unsigned short*)((char*)d_ws + x_batch + kvp_batch);
    for (int b = 0; b < BB; ++b) {
      ropekv_kernel<<<dim3(32), dim3(512), 0, stream>>>(
          h + (size_t)b * NN * DD, cs, sn, xw, kvp, HH);
      wkvt_kernel<<<dim3(HH * 4), dim3(512), 0, stream>>>(W, kvp, wkvt, HH);
      gemm_kernel<<<dim3(NN / 128, DD / 256, 1), dim3(256), 0, stream>>>(
          xw, wkvt, out + (size_t)b * NN * DD);
    }
  }
}

// Round 3
// 331.005 us; speedup vs baseline: 1.0150x; 1.0150x over previous
//
#include <hip/hip_runtime.h>
#include <hip/hip_bf16.h>
#include <stdint.h>

// Problem dims (fixed by reference)
#define BB 8
#define NN 8192
#define DD 512
#define HH 8
#define DHD 64
#define NCH 32   // kv partial chunks (each = 256 rows = 4 tiles of 64)

typedef __attribute__((ext_vector_type(8))) short bf16x8;
typedef __attribute__((ext_vector_type(4))) float f32x4;
typedef __attribute__((ext_vector_type(4))) float f4v;

__device__ __forceinline__ unsigned short f2bf(float f) {
  union { float f; unsigned int u; } v; v.f = f;
  return (unsigned short)((v.u + 0x7FFFu + ((v.u >> 16) & 1u)) >> 16);
}

__device__ __forceinline__ void async16(const void* g, void* l) {
  __builtin_amdgcn_global_load_lds(
      (const __attribute__((address_space(1))) void*)g,
      (__attribute__((address_space(3))) void*)l, 16, 0, 0);
}

// ---------------- Kernel 1: fused RoPE + cast + per-head X_h^T X_h partials ----
// (unchanged — single-variable experiment on the gemm)
__global__ __launch_bounds__(512, 2) void ropekv_kernel(
    const float* __restrict__ h, const float* __restrict__ cs,
    const float* __restrict__ sn, unsigned short* __restrict__ x,
    float* __restrict__ kvp, int nbh) {
  __shared__ __align__(16) unsigned int xt32[512 * 34];  // 69.6 KB
  int blk = blockIdx.x;
  int chunk = blk & 31, b = blk >> 5;
  int tid = threadIdx.x;
  int wave = tid >> 6, lane = tid & 63;
  int rpar = lane & 1;          // row parity within pair
  int g = lane >> 1;            // col-group [0,32): 8 fp32 cols each
  int cf = g * 8;               // fp32 col base in lo half [0,256)
  int l15 = lane & 15, q = lane >> 4;
  int hd = wave * 64;           // head d-base for MFMA phase
  size_t row0 = (size_t)b * NN + (size_t)chunk * 256;
  int n0 = chunk * 256;

  f32x4 acc[4][4];
#pragma unroll
  for (int i = 0; i < 4; ++i)
#pragma unroll
    for (int j = 0; j < 4; ++j) acc[i][j] = (f32x4){0.f, 0.f, 0.f, 0.f};

  f4v ha[4][2], hbv[4][2];

  auto loadt = [&](int t) {
#pragma unroll
    for (int p = 0; p < 4; ++p) {
      int r = p * 16 + wave * 2 + rpar;
      const float* hp = h + (row0 + t * 64 + r) * DD + cf;
      ha[p][0]  = __builtin_nontemporal_load((const f4v*)hp);
      ha[p][1]  = __builtin_nontemporal_load((const f4v*)(hp + 4));
      hbv[p][0] = __builtin_nontemporal_load((const f4v*)(hp + 256));
      hbv[p][1] = __builtin_nontemporal_load((const f4v*)(hp + 260));
    }
  };

  auto ropet = [&](int t) {
#pragma unroll
    for (int p = 0; p < 4; ++p) {
      int r = p * 16 + wave * 2 + rpar;
      int nr = n0 + t * 64 + r;
      const float* cp = cs + (size_t)nr * DD + cf;
      const float* sp = sn + (size_t)nr * DD + cf;
      f4v c0 = *(const f4v*)cp, c1 = *(const f4v*)(cp + 4);
      f4v s0 = *(const f4v*)sp, s1 = *(const f4v*)(sp + 4);
      f4v xl0 = ha[p][0] * c0 - hbv[p][0] * s0;
      f4v xl1 = ha[p][1] * c1 - hbv[p][1] * s1;
      f4v xh0 = hbv[p][0] * c0 + ha[p][0] * s0;
      f4v xh1 = hbv[p][1] * c1 + ha[p][1] * s1;
      unsigned ml[4], mh[4];
      ml[0] = (unsigned)f2bf(xl0.x) | ((unsigned)f2bf(xl0.y) << 16);
      ml[1] = (unsigned)f2bf(xl0.z) | ((unsigned)f2bf(xl0.w) << 16);
      ml[2] = (unsigned)f2bf(xl1.x) | ((unsigned)f2bf(xl1.y) << 16);
      ml[3] = (unsigned)f2bf(xl1.z) | ((unsigned)f2bf(xl1.w) << 16);
      mh[0] = (unsigned)f2bf(xh0.x) | ((unsigned)f2bf(xh0.y) << 16);
      mh[1] = (unsigned)f2bf(xh0.z) | ((unsigned)f2bf(xh0.w) << 16);
      mh[2] = (unsigned)f2bf(xh1.x) | ((unsigned)f2bf(xh1.y) << 16);
      mh[3] = (unsigned)f2bf(xh1.z) | ((unsigned)f2bf(xh1.w) << 16);
      unsigned short* xp = x + (row0 + t * 64 + r) * DD + cf;
      uint4 st0; st0.x = ml[0]; st0.y = ml[1]; st0.z = ml[2]; st0.w = ml[3];
      uint4 st1; st1.x = mh[0]; st1.y = mh[1]; st1.z = mh[2]; st1.w = mh[3];
      *(uint4*)xp         = st0;
      *(uint4*)(xp + 256) = st1;
      unsigned pk[8];
#pragma unroll
      for (int k = 0; k < 4; ++k) {
        unsigned mine = rpar ? mh[k] : ml[k];
        unsigned send = rpar ? ml[k] : mh[k];
        unsigned recv = (unsigned)__shfl_xor((int)send, 1, 64);
        if (!rpar) {
          pk[2 * k]     = (mine & 0xffffu) | (recv << 16);
          pk[2 * k + 1] = (mine >> 16) | (recv & 0xffff0000u);
        } else {
          pk[2 * k]     = (recv & 0xffffu) | (mine << 16);
          pk[2 * k + 1] = (recv >> 16) | (mine & 0xffff0000u);
        }
      }
      int np = p * 8 + wave;
      int dbase = cf + (rpar ? 256 : 0);
      int rot = (g >> 1) & 7;
#pragma unroll
      for (int w = 0; w < 8; ++w) {
        int jj = (w + rot) & 7;
        xt32[(dbase + jj) * 34 + np] = pk[jj];
      }
    }
  };

  loadt(0);
  for (int t = 0; t < 4; ++t) {
    ropet(t);
    __syncthreads();
    if (t < 3) loadt(t + 1);
    const unsigned short* xt16 = (const unsigned short*)xt32;
#pragma unroll
    for (int ks = 0; ks < 64; ks += 32) {
      bf16x8 af[4];
#pragma unroll
      for (int i = 0; i < 4; ++i)
        af[i] = *(const bf16x8*)&xt16[(hd + i * 16 + l15) * 68 + ks + q * 8];
#pragma unroll
      for (int i = 0; i < 4; ++i)
#pragma unroll
        for (int j = 0; j < 4; ++j)
          acc[i][j] = __builtin_amdgcn_mfma_f32_16x16x32_bf16(af[i], af[j], acc[i][j], 0, 0, 0);
    }
    __syncthreads();
  }

  int bh = b * 8 + wave;
  float* dst = kvp + ((size_t)chunk * nbh + bh) * 4096;
#pragma unroll
  for (int i = 0; i < 4; ++i)
#pragma unroll
    for (int j = 0; j < 4; ++j)
#pragma unroll
      for (int reg = 0; reg < 4; ++reg)
        dst[(i * 16 + q * 4 + reg) * 64 + j * 16 + l15] = acc[i][j][reg];
}

// ---------------- Kernel 2: sum kv partials once, WkvT[bh][e][f] = sum_d W[h*64+d][f]*kv[d][e]
// (unchanged)
__global__ __launch_bounds__(512, 2) void wkvt_kernel(
    const float* __restrict__ W, const float* __restrict__ kvp,
    unsigned short* __restrict__ wkvt, int nbh) {
  __shared__ float kvs[64 * 16];
  __shared__ __align__(16) float ws[64 * 512];
  int blk = blockIdx.x;
  int bh = blk >> 2, eq = blk & 3;
  int b = bh >> 3, hh = bh & 7;
  int tid = threadIdx.x;
  if (tid < 256) {
    int idx = tid * 4;
    int d = idx >> 4, ec = idx & 15;
    f4v s = (f4v){0.f, 0.f, 0.f, 0.f};
    for (int c = 0; c < NCH; ++c)
      s += *(const f4v*)&kvp[((size_t)c * nbh + bh) * 4096 + d * 64 + eq * 16 + ec];
    *(f4v*)&kvs[idx] = s;
  }
#pragma unroll
  for (int i = 0; i < 16; ++i) {
    int idx = i * 2048 + tid * 4;
    *(f4v*)&ws[idx] = *(const f4v*)&W[(size_t)(hh * DHD + (idx >> 9)) * DD + (idx & 511)];
  }
  __syncthreads();
  int el = tid & 15, fg = tid >> 4;
  f4v av[4];
#pragma unroll
  for (int k = 0; k < 4; ++k) av[k] = (f4v){0.f, 0.f, 0.f, 0.f};
#pragma unroll 8
  for (int d = 0; d < 64; ++d) {
    float kvv = kvs[d * 16 + el];
    const f4v* wr = (const f4v*)&ws[d * DD + fg * 16];
#pragma unroll
    for (int k = 0; k < 4; ++k) av[k] += wr[k] * kvv;
  }
  unsigned short tb[16];
#pragma unroll
  for (int k = 0; k < 4; ++k) {
    tb[k * 4 + 0] = f2bf(av[k].x); tb[k * 4 + 1] = f2bf(av[k].y);
    tb[k * 4 + 2] = f2bf(av[k].z); tb[k * 4 + 3] = f2bf(av[k].w);
  }
  size_t ob = ((size_t)b * DD + hh * DHD + eq * 16 + el) * DD + fg * 16;
  *(uint4*)&wkvt[ob]     = *(uint4*)&tb[0];
  *(uint4*)&wkvt[ob + 8] = *(uint4*)&tb[8];
}

// ---------------- Kernel 3: out[b] = x_b [8192x512] @ WkvT_b^T ----
// 256x256 tile, 8 waves (2M x 4N, each 128x64), BK=64, 8-phase schedule
// (T2 swizzle + T3/T4 counted vmcnt + T5 setprio), 128 KiB LDS (2-tile dbuf,
// A/B split in 128-row halves). K=512 -> 8 K-tiles -> 4 iters of 8 phases.
// Stage schedule (slot-freeness verified): phase j stages
//   j0:B1(t+1) j1:A1(t+1) j2:B0(t+2) j3:A0(t+2) j4:B1(t+2) j5:A1(t+2) j6:B0(t+3) j7:A0(t+3)
// vmcnt(4) (=2 half-tiles in flight) only at j3/j7; drains to 0 only at i=3,j3.
// LDS swizzle: 16B-slot ^= (row&7) applied on pre-swizzled GLOBAL source (linear
// LDS dest, m173 pattern) and on ds_read addr -> 2-way (free) reads.
// Tables are constexpr so every phase's stage target folds at compile time
// (NOT __constant__ memory, which the compiler cannot fold -> runtime branch).
constexpr int c_stM[8] = {0, 1, 0, 1, 0, 1, 0, 1};  // 0=B, 1=A
constexpr int c_stP[8] = {1, 1, 0, 0, 0, 0, 1, 1};  // dest tile parity
constexpr int c_stH[8] = {1, 1, 0, 0, 1, 1, 0, 0};  // dest half
constexpr int c_stO[8] = {1, 1, 2, 2, 2, 2, 3, 3};  // tile offset from 2i

__global__ __launch_bounds__(512, 2) void gemm_kernel(const unsigned short* __restrict__ x,
                                                      const unsigned short* __restrict__ wkvt,
                                                      float* __restrict__ out) {
  __shared__ __align__(16) unsigned short Ab[2][2][128 * 64];  // [tile parity][half] 64 KB
  __shared__ __align__(16) unsigned short Bb[2][2][128 * 64];  // 64 KB
  int u = blockIdx.x;
  int cpx = gridDim.x >> 3;
  int l = (u & 7) * cpx + (u >> 3);     // bijective XCD swizzle (nwg % 8 == 0)
  int ct = l & 1, mt = (l >> 1) & 31, bz = l >> 6;
  int tid = threadIdx.x, wave = tid >> 6, lane = tid & 63;
  int wm = wave & 1, wn = wave >> 1;    // wave tile: rows wm*128+[0,128), cols wn*64+[0,64)
  int l15 = lane & 15, q = lane >> 4;
  const unsigned short* Ag = x    + ((size_t)bz * NN + mt * 256) * DD;
  const unsigned short* Bg = wkvt + ((size_t)bz * DD + ct * 256) * DD;

  // staging: thread covers 16B unit u=tid (rows 0-63) and 512+tid (rows 64-127)
  // of a [128 row][8 slot] half; source slot pre-swizzled so LDS stays linear.
  int row0 = tid >> 3,         ss0 = (tid & 7) ^ (row0 & 7);
  int row1 = (512 + tid) >> 3, ss1 = ((512 + tid) & 7) ^ (row1 & 7);
  const unsigned short* At0 = Ag + (size_t)row0 * DD + ss0 * 8;
  const unsigned short* At1 = Ag + (size_t)row1 * DD + ss1 * 8;
  const unsigned short* Bt0 = Bg + (size_t)row0 * DD + ss0 * 8;
  const unsigned short* Bt1 = Bg + (size_t)row1 * DD + ss1 * 8;

  auto stgA = [&](int P, int hf, int kt) {
    async16(At0 + (size_t)hf * 128 * DD + kt * 64, &Ab[P][hf][wave * 512]);
    async16(At1 + (size_t)hf * 128 * DD + kt * 64, &Ab[P][hf][4096 + wave * 512]);
  };
  auto stgB = [&](int P, int hf, int kt) {
    async16(Bt0 + (size_t)hf * 128 * DD + kt * 64, &Bb[P][hf][wave * 512]);
    async16(Bt1 + (size_t)hf * 128 * DD + kt * 64, &Bb[P][hf][4096 + wave * 512]);
  };

  // ds_read swizzled slot offsets (shorts): slot j ^ (row&7), row&7 == l15&7
  int sw0 = ((q ^ (l15 & 7)) << 3);
  int sw1 = (((4 + q) ^ (l15 & 7)) << 3);

  bf16x8 Ar[4][2], Br[4][2];
  auto loadA4 = [&](int P, int a) {
#pragma unroll
    for (int f = 0; f < 4; ++f) {
      int r = (a * 64 + f * 16 + l15) * 64;
      Ar[f][0] = *(const bf16x8*)&Ab[P][wm][r + sw0];
      Ar[f][1] = *(const bf16x8*)&Ab[P][wm][r + sw1];
    }
  };
  auto loadB2 = [&](int P, int n0) {
#pragma unroll
    for (int f = 0; f < 2; ++f) {
      int r = ((wn & 1) * 64 + (n0 + f) * 16 + l15) * 64;
      Br[n0 + f][0] = *(const bf16x8*)&Bb[P][wn >> 1][r + sw0];
      Br[n0 + f][1] = *(const bf16x8*)&Bb[P][wn >> 1][r + sw1];
    }
  };

  f32x4 acc[8][4];
#pragma unroll
  for (int i = 0; i < 8; ++i)
#pragma unroll
    for (int j = 0; j < 4; ++j) acc[i][j] = (f32x4){0.f, 0.f, 0.f, 0.f};

  // prologue: stage tile0 fully + tile1 h0 (6 half-tiles = 12 loads/wave);
  // vmcnt(4) waits for the 8 oldest = all of tile0.
  stgB(0, 0, 0); stgA(0, 0, 0); stgB(0, 1, 0); stgA(0, 1, 0);
  stgB(1, 0, 1); stgA(1, 0, 1);
  asm volatile("s_waitcnt vmcnt(4)" ::: "memory");
  __builtin_amdgcn_s_barrier();

#pragma unroll
  for (int i = 0; i < 4; ++i) {
#pragma unroll
    for (int j = 0; j < 8; ++j) {
      constexpr int jm[8] = {0, 1, 0, 1, 0, 1, 0, 1};
      (void)jm;
      int P = j >> 2;              // computing tile parity (tile 2i+P)
      int a = (j >> 1) & 1;        // m-quadrant
      int b2 = (j & 1) * 2;        // n-pair base
      // ds reads for this phase (issued pre-barrier; slots staged >=1 group ago)
      if ((j & 3) == 0) loadB2(P, 0);
      if ((j & 3) == 1) loadB2(P, 2);
      if ((j & 1) == 0) loadA4(P, a);
      // stage exactly one half-tile (compile-time folded; skipped past tile 7)
      if (2 * i + c_stO[j] < 8) {
        if (c_stM[j]) stgA(c_stP[j], c_stH[j], 2 * i + c_stO[j]);
        else          stgB(c_stP[j], c_stH[j], 2 * i + c_stO[j]);
      }
      __builtin_amdgcn_s_barrier();
      asm volatile("s_waitcnt lgkmcnt(0)" ::: "memory");
      __builtin_amdgcn_sched_barrier(0);
      __builtin_amdgcn_s_setprio(1);
#pragma unroll
      for (int f = 0; f < 4; ++f)
#pragma unroll
        for (int nn = 0; nn < 2; ++nn) {
          acc[a * 4 + f][b2 + nn] = __builtin_amdgcn_mfma_f32_16x16x32_bf16(
              Ar[f][0], Br[b2 + nn][0], acc[a * 4 + f][b2 + nn], 0, 0, 0);
          acc[a * 4 + f][b2 + nn] = __builtin_amdgcn_mfma_f32_16x16x32_bf16(
              Ar[f][1], Br[b2 + nn][1], acc[a * 4 + f][b2 + nn], 0, 0, 0);
        }
      __builtin_amdgcn_s_setprio(0);
      // counted waits at group boundaries only (never drain mid-pipeline);
      // i=3,j3 is the exception: tile7's own halves are the newest issues.
      if (i == 3 && j == 3) {
        asm volatile("s_waitcnt vmcnt(0)" ::: "memory");
      } else if ((j & 3) == 3) {
        asm volatile("s_waitcnt vmcnt(4)" ::: "memory");
      }
      __builtin_amdgcn_s_barrier();
    }
  }

  float* ob = out + ((size_t)bz * NN + mt * 256 + wm * 128) * DD + ct * 256 + wn * 64;
#pragma unroll
  for (int f = 0; f < 4; ++f) {
#pragma unroll
    for (int a = 0; a < 2; ++a)
#pragma unroll
      for (int nn = 0; nn < 4; ++nn) {
        int row = a * 64 + f * 16 + q * 4;
        int col = nn * 16 + l15;
#pragma unroll
        for (int reg = 0; reg < 4; ++reg)
          __builtin_nontemporal_store(acc[a * 4 + f][nn][reg],
                                      &ob[(size_t)(row + reg) * DD + col]);
      }
  }
}

extern "C" void kernel_launch(void* const* d_in, const int* in_sizes, int n_in,
                              void* d_out, int out_size, void* d_ws, size_t ws_size,
                              hipStream_t stream) {
  (void)in_sizes; (void)n_in; (void)out_size;
  const float* h  = (const float*)d_in[0];
  const float* W  = (const float*)d_in[1];
  const float* cs = (const float*)d_in[2];
  const float* sn = (const float*)d_in[3];
  float* out = (float*)d_out;

  const size_t x_full     = (size_t)BB * NN * DD * 2;               // 67.1 MB
  const size_t kvp_full   = (size_t)NCH * BB * HH * DHD * DHD * 4;  // 33.6 MB
  const size_t wkvt_full  = (size_t)BB * DD * DD * 2;               // 4.2 MB
  const size_t x_batch    = (size_t)NN * DD * 2;                    // 8.4 MB
  const size_t kvp_batch  = (size_t)NCH * HH * DHD * DHD * 4;       // 4.2 MB
  const size_t wkvt_batch = (size_t)DD * DD * 2;                    // 524 KB

  if (ws_size >= x_full + kvp_full + wkvt_full) {
    // -------- full path: 3 launches --------
    unsigned short* xw   = (unsigned short*)d_ws;
    float*          kvp  = (float*)((char*)d_ws + x_full);
    unsigned short* wkvt = (unsigned short*)((char*)d_ws + x_full + kvp_full);
    ropekv_kernel<<<dim3(BB * 32), dim3(512), 0, stream>>>(h, cs, sn, xw, kvp, BB * HH);
    wkvt_kernel<<<dim3(BB * HH * 4), dim3(512), 0, stream>>>(W, kvp, wkvt, BB * HH);
    gemm_kernel<<<dim3((NN / 256) * (DD / 256) * BB), dim3(512), 0, stream>>>(xw, wkvt, out);
  } else {
    // -------- per-batch fallback (~13 MB workspace) --------
    unsigned short* xw   = (unsigned short*)d_ws;
    float*          kvp  = (float*)((char*)d_ws + x_batch);
    unsigned short* wkvt = (unsigned short*)((char*)d_ws + x_batch + kvp_batch);
    for (int b = 0; b < BB; ++b) {
      ropekv_kernel<<<dim3(32), dim3(512), 0, stream>>>(
          h + (size_t)b * NN * DD, cs, sn, xw, kvp, HH);
      wkvt_kernel<<<dim3(HH * 4), dim3(512), 0, stream>>>(W, kvp, wkvt, HH);
      gemm_kernel<<<dim3((NN / 256) * (DD / 256)), dim3(512), 0, stream>>>(
          xw, wkvt, out + (size_t)b * NN * DD);
    }
  }
}